// Round 7
// baseline (1098.036 us; speedup 1.0000x reference)
//
#include <hip/hip_runtime.h>
#include <math.h>

// Problem constants
#define BB 16
#define CC 512
#define LL 8192
#define HH 32            // CC / 16
#define BC (BB * CC)
#define NBLK 1024        // 4 blocks/CU * 256 CU (cooperative-resident)
#define NTHR 256
#define NITER 8          // rows per block: 1024*8 = 8192 rows

typedef float fv4 __attribute__((ext_vector_type(4)));

// ---------------------------------------------------------------------------
// Single-pass SE: each block holds ONE row (32 KiB, 32 VGPRs/thread) in
// registers across the per-batch sync, so x is read from HBM exactly once
// and out written once (512 MiB total).  Sync = per-batch done[] counters
// (release add / acquire poll, agent scope).  No grid-wide lockstep: the 2
// batches in flight per iteration are independent, and polling blocks sleep
// while other blocks on the CU stream.
// ---------------------------------------------------------------------------
__global__ __launch_bounds__(NTHR, 4) void k_se_regres(
        const float* __restrict__ x,
        const float* __restrict__ w1, const float* __restrict__ b1,
        const float* __restrict__ w2, const float* __restrict__ b2,
        float* __restrict__ out,
        float* __restrict__ s,            // BC floats (ws)
        unsigned int* __restrict__ done)  // BB counters (ws, zeroed per call)
{
    const int g   = blockIdx.x;       // 0..1023
    const int tid = threadIdx.x;      // 0..255

    __shared__ float red[4];
    __shared__ float sh_s[CC];
    __shared__ float part[HH][9];     // +1 pad
    __shared__ float sh_h[HH];
    __shared__ float sh_gate;

    for (int k = 0; k < NITER; ++k) {
        const int row = k * NBLK + g;     // 0..8191
        const int b   = row >> 9;         // batch

        // ---- Phase A: load row into registers, compute mean ----
        const fv4* xr = (const fv4*)(x + (size_t)row * LL);
        fv4 v[8];
#pragma unroll
        for (int i = 0; i < 8; ++i)
            v[i] = __builtin_nontemporal_load(&xr[i * NTHR + tid]);

        float acc = 0.0f;
#pragma unroll
        for (int i = 0; i < 8; ++i)
            acc += (v[i].x + v[i].y) + (v[i].z + v[i].w);
#pragma unroll
        for (int off = 32; off > 0; off >>= 1)
            acc += __shfl_down(acc, off, 64);
        if ((tid & 63) == 0) red[tid >> 6] = acc;
        __syncthreads();
        if (tid == 0) {
            float t = (red[0] + red[1]) + (red[2] + red[3]);
            __hip_atomic_store(&s[row], t * (1.0f / (float)LL),
                               __ATOMIC_RELAXED, __HIP_MEMORY_SCOPE_AGENT);
            __hip_atomic_fetch_add(&done[b], 1u, __ATOMIC_RELEASE,
                                   __HIP_MEMORY_SCOPE_AGENT);
        }

        // ---- wait for all 512 means of batch b ----
        if (tid == 0) {
            while (__hip_atomic_load(&done[b], __ATOMIC_ACQUIRE,
                                     __HIP_MEMORY_SCOPE_AGENT) < (unsigned)CC) {
                __builtin_amdgcn_s_sleep(2);
            }
        }
        __syncthreads();

        // ---- Phase B: gates (redundant per block, tiny) ----
        sh_s[tid]       = __hip_atomic_load(&s[b * CC + tid],
                              __ATOMIC_RELAXED, __HIP_MEMORY_SCOPE_AGENT);
        sh_s[tid + 256] = __hip_atomic_load(&s[b * CC + tid + 256],
                              __ATOMIC_RELAXED, __HIP_MEMORY_SCOPE_AGENT);
        __syncthreads();
        {
            const int j   = tid >> 3;     // 0..31
            const int seg = tid & 7;      // 0..7, 64 c's each
            const float* srow = sh_s + seg * 64;
            const float* wrow = w1 + (size_t)j * CC + seg * 64;
            float pacc = 0.0f;
#pragma unroll
            for (int c = 0; c < 64; ++c) pacc += srow[c] * wrow[c];
            part[j][seg] = pacc;
        }
        __syncthreads();
        if (tid < HH) {
            float h = b1[tid];
#pragma unroll
            for (int q = 0; q < 8; ++q) h += part[tid][q];
            sh_h[tid] = h > 0.0f ? h : 0.0f;
        }
        __syncthreads();
        if (tid == 0) {
            const int c = row & (CC - 1);
            const float* wrow = w2 + (size_t)c * HH;
            float z = b2[c];
#pragma unroll
            for (int q = 0; q < HH; ++q) z += sh_h[q] * wrow[q];
            sh_gate = 1.0f / (1.0f + expf(-z));
        }
        __syncthreads();

        // ---- Phase C: scale registers, nt-store ----
        const float gate = sh_gate;
        fv4* orr = (fv4*)(out + (size_t)row * LL);
#pragma unroll
        for (int i = 0; i < 8; ++i) {
            fv4 w = v[i] * gate;
            __builtin_nontemporal_store(w, &orr[i * NTHR + tid]);
        }
        __syncthreads();   // protect red[]/sh_* reuse next iteration
    }
}

// ---------------------------------------------------------------------------
// Fallback path (proven R3 kernels) in case the cooperative launch is
// rejected — correctness first.
// ---------------------------------------------------------------------------
__global__ __launch_bounds__(256) void k_mean(const float* __restrict__ x,
                                              float* __restrict__ s) {
    const int row = blockIdx.x;
    const int tid = threadIdx.x;
    const fv4* xr = (const fv4*)(x + (size_t)row * LL);
    float acc = 0.0f;
#pragma unroll
    for (int i = 0; i < 8; ++i) {
        fv4 v = xr[i * 256 + tid];
        acc += (v.x + v.y) + (v.z + v.w);
    }
#pragma unroll
    for (int off = 32; off > 0; off >>= 1)
        acc += __shfl_down(acc, off, 64);
    __shared__ float part[4];
    if ((tid & 63) == 0) part[tid >> 6] = acc;
    __syncthreads();
    if (tid == 0)
        s[row] = ((part[0] + part[1]) + (part[2] + part[3])) * (1.0f / (float)LL);
}

__global__ __launch_bounds__(256) void k_scale_fused(
        const float* __restrict__ x,  const float* __restrict__ s,
        const float* __restrict__ w1, const float* __restrict__ b1,
        const float* __restrict__ w2, const float* __restrict__ b2,
        float* __restrict__ out) {
    const int bid   = (int)gridDim.x - 1 - (int)blockIdx.x;
    const int b     = bid >> 7;
    const int chunk = bid & 127;
    const int tid   = threadIdx.x;
    __shared__ float partial[HH][9];
    __shared__ float h[HH];
    __shared__ float g4[4];
    {
        const int j   = tid >> 3;
        const int seg = tid & 7;
        const float* srow = s  + b * CC + seg * 64;
        const float* wrow = w1 + (size_t)j * CC + seg * 64;
        float p = 0.0f;
#pragma unroll
        for (int c = 0; c < 64; ++c) p += srow[c] * wrow[c];
        partial[j][seg] = p;
    }
    __syncthreads();
    if (tid < HH) {
        float t = b1[tid];
#pragma unroll
        for (int q = 0; q < 8; ++q) t += partial[tid][q];
        h[tid] = t > 0.0f ? t : 0.0f;
    }
    __syncthreads();
    if (tid < 4) {
        const int c = chunk * 4 + tid;
        const float* wrow = w2 + (size_t)c * HH;
        float z = b2[c];
#pragma unroll
        for (int j = 0; j < HH; ++j) z += h[j] * wrow[j];
        g4[tid] = 1.0f / (1.0f + expf(-z));
    }
    __syncthreads();
#pragma unroll
    for (int r = 0; r < 4; ++r) {
        const int c = chunk * 4 + r;
        const size_t off = ((size_t)b * CC + c) * (size_t)LL;
        const fv4* xr  = (const fv4*)(x + off);
        fv4*       orr = (fv4*)(out + off);
        const float gate = g4[r];
#pragma unroll
        for (int i = 0; i < 8; ++i) {
            fv4 v = xr[i * 256 + tid];
            v *= gate;
            __builtin_nontemporal_store(v, &orr[i * 256 + tid]);
        }
    }
}

extern "C" void kernel_launch(void* const* d_in, const int* in_sizes, int n_in,
                              void* d_out, int out_size, void* d_ws, size_t ws_size,
                              hipStream_t stream) {
    const float* x  = (const float*)d_in[0];
    const float* w1 = (const float*)d_in[1];
    const float* b1 = (const float*)d_in[2];
    const float* w2 = (const float*)d_in[3];
    const float* b2 = (const float*)d_in[4];
    float* out = (float*)d_out;

    float* s = (float*)d_ws;                       // BC floats
    unsigned int* done = (unsigned int*)(s + BC);  // BB counters

    hipMemsetAsync(done, 0, BB * sizeof(unsigned int), stream);

    void* args[] = {(void*)&x, (void*)&w1, (void*)&b1, (void*)&w2,
                    (void*)&b2, (void*)&out, (void*)&s, (void*)&done};
    hipError_t err = hipLaunchCooperativeKernel((const void*)k_se_regres,
                                                dim3(NBLK), dim3(NTHR),
                                                args, 0, stream);
    if (err != hipSuccess) {
        // deterministic fallback: proven two-kernel path
        k_mean       <<<BC,   256, 0, stream>>>(x, s);
        k_scale_fused<<<BC/4, 256, 0, stream>>>(x, s, w1, b1, w2, b2, out);
    }
}

// Round 8
// 842.280 us; speedup vs baseline: 1.3036x; 1.3036x over previous
//
#include <hip/hip_runtime.h>
#include <math.h>

// Problem constants
#define BB 16
#define CC 512
#define LL 8192
#define HH 32            // CC / 16
#define BC (BB * CC)
#define NBLK 1024        // 4 blocks/CU * 256 CU (cooperative-resident)
#define NTHR 256
#define NITER 8          // rows per block: 1024*8 = 8192
#define NSUB 64          // sub-counters per batch
#define SUBSTRIDE 32     // uints per sub-counter slot = 128 B (own line)

typedef float fv4 __attribute__((ext_vector_type(4)));

// ---- Phase A: load row into regs, mean, post to spread counters ----
__device__ __forceinline__ void mean_post(
        const float* __restrict__ x, float* __restrict__ s,
        unsigned int* __restrict__ sub, int row, int tid,
        fv4 (&v)[8], float* red)
{
    const fv4* xr = (const fv4*)(x + (size_t)row * LL);
#pragma unroll
    for (int i = 0; i < 8; ++i)
        v[i] = __builtin_nontemporal_load(&xr[i * NTHR + tid]);
    float acc = 0.0f;
#pragma unroll
    for (int i = 0; i < 8; ++i)
        acc += (v[i].x + v[i].y) + (v[i].z + v[i].w);
#pragma unroll
    for (int off = 32; off > 0; off >>= 1)
        acc += __shfl_down(acc, off, 64);
    if ((tid & 63) == 0) red[tid >> 6] = acc;
    __syncthreads();
    if (tid == 0) {
        const float t = (red[0] + red[1]) + (red[2] + red[3]);
        const int b  = row >> 9;
        const int rb = row & (CC - 1);
        __hip_atomic_store(&s[row], t * (1.0f / (float)LL),
                           __ATOMIC_RELAXED, __HIP_MEMORY_SCOPE_AGENT);
        __hip_atomic_fetch_add(
            &sub[(size_t)b * NSUB * SUBSTRIDE + (size_t)(rb >> 3) * SUBSTRIDE],
            1u, __ATOMIC_RELEASE, __HIP_MEMORY_SCOPE_AGENT);
    }
    __syncthreads();     // red[] safe for reuse
}

// ---- Phase B+C: wait for batch, gates, scale regs, nt-store ----
__device__ __forceinline__ void wait_gate_scale(
        const float* __restrict__ s, unsigned int* __restrict__ sub,
        const float* __restrict__ w1, const float* __restrict__ b1,
        const float* __restrict__ w2, const float* __restrict__ b2,
        float* __restrict__ out, int row, int tid,
        fv4 (&v)[8], float* sh_s, float (*part)[9], float* sh_h,
        float* sh_gate)
{
    const int b = row >> 9;

    // every thread polls its lane's sub-counter -> per-thread acquire order
    {
        const unsigned int* sc = sub + (size_t)b * NSUB * SUBSTRIDE
                                     + (size_t)(tid & 63) * SUBSTRIDE;
        while (true) {
            unsigned int tot = __hip_atomic_load(sc, __ATOMIC_ACQUIRE,
                                                 __HIP_MEMORY_SCOPE_AGENT);
#pragma unroll
            for (int off = 32; off > 0; off >>= 1)
                tot += __shfl_down(tot, off, 64);
            tot = __shfl(tot, 0, 64);
            if (tot >= (unsigned)CC) break;
            __builtin_amdgcn_s_sleep(16);
        }
    }
    __syncthreads();

    sh_s[tid]       = __hip_atomic_load(&s[b * CC + tid],
                          __ATOMIC_RELAXED, __HIP_MEMORY_SCOPE_AGENT);
    sh_s[tid + 256] = __hip_atomic_load(&s[b * CC + tid + 256],
                          __ATOMIC_RELAXED, __HIP_MEMORY_SCOPE_AGENT);
    __syncthreads();
    {
        const int j   = tid >> 3;     // 0..31
        const int seg = tid & 7;      // 0..7, 64 c's each
        const float* srow = sh_s + seg * 64;
        const float* wrow = w1 + (size_t)j * CC + seg * 64;
        float pacc = 0.0f;
#pragma unroll
        for (int c = 0; c < 64; ++c) pacc += srow[c] * wrow[c];
        part[j][seg] = pacc;
    }
    __syncthreads();
    if (tid < HH) {
        float h = b1[tid];
#pragma unroll
        for (int q = 0; q < 8; ++q) h += part[tid][q];
        sh_h[tid] = h > 0.0f ? h : 0.0f;
    }
    __syncthreads();
    if (tid == 0) {
        const int c = row & (CC - 1);
        const float* wrow = w2 + (size_t)c * HH;
        float z = b2[c];
#pragma unroll
        for (int q = 0; q < HH; ++q) z += sh_h[q] * wrow[q];
        *sh_gate = 1.0f / (1.0f + expf(-z));
    }
    __syncthreads();

    const float gate = *sh_gate;
    fv4* orr = (fv4*)(out + (size_t)row * LL);
#pragma unroll
    for (int i = 0; i < 8; ++i) {
        fv4 w = v[i] * gate;
        __builtin_nontemporal_store(w, &orr[i * NTHR + tid]);
    }
    __syncthreads();
}

// ---------------------------------------------------------------------------
// Register-resident single-pass SE, software-pipelined: mean(k+1) is issued
// BEFORE waiting on batch(k), so straggler waits overlap the next stream.
// ---------------------------------------------------------------------------
__global__ __launch_bounds__(NTHR, 4) void k_se_pipe(
        const float* __restrict__ x,
        const float* __restrict__ w1, const float* __restrict__ b1,
        const float* __restrict__ w2, const float* __restrict__ b2,
        float* __restrict__ out,
        float* __restrict__ s,            // BC floats (ws)
        unsigned int* __restrict__ sub)   // BB*NSUB*SUBSTRIDE uints (zeroed)
{
    const int g   = blockIdx.x;
    const int tid = threadIdx.x;

    __shared__ float red[4];
    __shared__ float sh_s[CC];
    __shared__ float part[HH][9];
    __shared__ float sh_h[HH];
    __shared__ float sh_gate;

    fv4 va[8], vb[8];

    mean_post(x, s, sub, g, tid, va, red);
#pragma unroll
    for (int k = 0; k < NITER; k += 2) {
        if (k + 1 < NITER)
            mean_post(x, s, sub, (k + 1) * NBLK + g, tid, vb, red);
        wait_gate_scale(s, sub, w1, b1, w2, b2, out, k * NBLK + g, tid,
                        va, sh_s, part, sh_h, &sh_gate);
        if (k + 2 < NITER)
            mean_post(x, s, sub, (k + 2) * NBLK + g, tid, va, red);
        if (k + 1 < NITER)
            wait_gate_scale(s, sub, w1, b1, w2, b2, out, (k + 1) * NBLK + g,
                            tid, vb, sh_s, part, sh_h, &sh_gate);
    }
}

// ---------------------------------------------------------------------------
// Fallback path (proven R3 kernels) if the cooperative launch is rejected.
// ---------------------------------------------------------------------------
__global__ __launch_bounds__(256) void k_mean(const float* __restrict__ x,
                                              float* __restrict__ s) {
    const int row = blockIdx.x;
    const int tid = threadIdx.x;
    const fv4* xr = (const fv4*)(x + (size_t)row * LL);
    float acc = 0.0f;
#pragma unroll
    for (int i = 0; i < 8; ++i) {
        fv4 v = xr[i * 256 + tid];
        acc += (v.x + v.y) + (v.z + v.w);
    }
#pragma unroll
    for (int off = 32; off > 0; off >>= 1)
        acc += __shfl_down(acc, off, 64);
    __shared__ float part[4];
    if ((tid & 63) == 0) part[tid >> 6] = acc;
    __syncthreads();
    if (tid == 0)
        s[row] = ((part[0] + part[1]) + (part[2] + part[3])) * (1.0f / (float)LL);
}

__global__ __launch_bounds__(256) void k_scale_fused(
        const float* __restrict__ x,  const float* __restrict__ s,
        const float* __restrict__ w1, const float* __restrict__ b1,
        const float* __restrict__ w2, const float* __restrict__ b2,
        float* __restrict__ out) {
    const int bid   = (int)gridDim.x - 1 - (int)blockIdx.x;
    const int b     = bid >> 7;
    const int chunk = bid & 127;
    const int tid   = threadIdx.x;
    __shared__ float partial[HH][9];
    __shared__ float h[HH];
    __shared__ float g4[4];
    {
        const int j   = tid >> 3;
        const int seg = tid & 7;
        const float* srow = s  + b * CC + seg * 64;
        const float* wrow = w1 + (size_t)j * CC + seg * 64;
        float p = 0.0f;
#pragma unroll
        for (int c = 0; c < 64; ++c) p += srow[c] * wrow[c];
        partial[j][seg] = p;
    }
    __syncthreads();
    if (tid < HH) {
        float t = b1[tid];
#pragma unroll
        for (int q = 0; q < 8; ++q) t += partial[tid][q];
        h[tid] = t > 0.0f ? t : 0.0f;
    }
    __syncthreads();
    if (tid < 4) {
        const int c = chunk * 4 + tid;
        const float* wrow = w2 + (size_t)c * HH;
        float z = b2[c];
#pragma unroll
        for (int j = 0; j < HH; ++j) z += h[j] * wrow[j];
        g4[tid] = 1.0f / (1.0f + expf(-z));
    }
    __syncthreads();
#pragma unroll
    for (int r = 0; r < 4; ++r) {
        const int c = chunk * 4 + r;
        const size_t off = ((size_t)b * CC + c) * (size_t)LL;
        const fv4* xr  = (const fv4*)(x + off);
        fv4*       orr = (fv4*)(out + off);
        const float gate = g4[r];
#pragma unroll
        for (int i = 0; i < 8; ++i) {
            fv4 v = xr[i * 256 + tid];
            v *= gate;
            __builtin_nontemporal_store(v, &orr[i * 256 + tid]);
        }
    }
}

extern "C" void kernel_launch(void* const* d_in, const int* in_sizes, int n_in,
                              void* d_out, int out_size, void* d_ws, size_t ws_size,
                              hipStream_t stream) {
    const float* x  = (const float*)d_in[0];
    const float* w1 = (const float*)d_in[1];
    const float* b1 = (const float*)d_in[2];
    const float* w2 = (const float*)d_in[3];
    const float* b2 = (const float*)d_in[4];
    float* out = (float*)d_out;

    float* s = (float*)d_ws;                       // BC floats
    unsigned int* sub = (unsigned int*)(s + BC);   // BB*NSUB*SUBSTRIDE uints

    hipMemsetAsync(sub, 0, (size_t)BB * NSUB * SUBSTRIDE * sizeof(unsigned int),
                   stream);

    void* args[] = {(void*)&x, (void*)&w1, (void*)&b1, (void*)&w2,
                    (void*)&b2, (void*)&out, (void*)&s, (void*)&sub};
    hipError_t err = hipLaunchCooperativeKernel((const void*)k_se_pipe,
                                                dim3(NBLK), dim3(NTHR),
                                                args, 0, stream);
    if (err != hipSuccess) {
        k_mean       <<<BC,   256, 0, stream>>>(x, s);
        k_scale_fused<<<BC/4, 256, 0, stream>>>(x, s, w1, b1, w2, b2, out);
    }
}

// Round 9
// 656.452 us; speedup vs baseline: 1.6727x; 1.2831x over previous
//
#include <hip/hip_runtime.h>
#include <math.h>

// Problem constants
#define BB 16
#define CC 512
#define LL 8192
#define HH 32            // CC / 16
#define BC (BB * CC)
#define NBLK 1024        // 4 blocks/CU * 256 CU (cooperative-resident)
#define NTHR 256
#define NITER 8          // rows per block: 1024*8 = 8192
#define NSUB 16          // spread sub-counters per batch
#define SUBSTRIDE 32     // uints per sub-counter = 128 B (own cacheline)

typedef float fv4 __attribute__((ext_vector_type(4)));

// ---------------------------------------------------------------------------
// Single-pass SE, register-resident row (32 KiB/block), detoxified sync:
//   release: relaxed s-store -> ONE release fence -> relaxed RMW on a spread
//            sub-counter (16 lines/batch, 32 adds each).
//   acquire: wave-0 polls with RELAXED agent loads (coherence-point reads,
//            NO cache invalidate), then ONE acquire fence after success.
// This removes the buffer_inv storm that capped R4/R7/R8 at ~470 GB/s.
// ---------------------------------------------------------------------------
__global__ __launch_bounds__(NTHR, 4) void k_se_v3(
        const float* __restrict__ x,
        const float* __restrict__ w1, const float* __restrict__ b1,
        const float* __restrict__ w2, const float* __restrict__ b2,
        float* __restrict__ out,
        float* __restrict__ s,            // BC floats (ws)
        unsigned int* __restrict__ sub)   // BB*NSUB*SUBSTRIDE uints (zeroed)
{
    const int g   = blockIdx.x;       // 0..1023
    const int tid = threadIdx.x;      // 0..255

    __shared__ float red[4];
    __shared__ float sh_s[CC];
    __shared__ float part[HH][9];     // +1 pad
    __shared__ float sh_h[HH];
    __shared__ float sh_gate;

    for (int k = 0; k < NITER; ++k) {
        const int row = k * NBLK + g;     // 0..8191
        const int b   = row >> 9;         // batch

        // ---- Phase A: load row into registers, compute mean ----
        const fv4* xr = (const fv4*)(x + (size_t)row * LL);
        fv4 v[8];
#pragma unroll
        for (int i = 0; i < 8; ++i)
            v[i] = __builtin_nontemporal_load(&xr[i * NTHR + tid]);

        float acc = 0.0f;
#pragma unroll
        for (int i = 0; i < 8; ++i)
            acc += (v[i].x + v[i].y) + (v[i].z + v[i].w);
#pragma unroll
        for (int off = 32; off > 0; off >>= 1)
            acc += __shfl_down(acc, off, 64);
        if ((tid & 63) == 0) red[tid >> 6] = acc;
        __syncthreads();

        if (tid == 0) {
            const float t = (red[0] + red[1]) + (red[2] + red[3]);
            __hip_atomic_store(&s[row], t * (1.0f / (float)LL),
                               __ATOMIC_RELAXED, __HIP_MEMORY_SCOPE_AGENT);
            __builtin_amdgcn_fence(__ATOMIC_RELEASE, "agent");   // one wb
            const int line = (row & (CC - 1)) >> 5;              // 0..15
            __hip_atomic_fetch_add(
                &sub[((size_t)b * NSUB + line) * SUBSTRIDE], 1u,
                __ATOMIC_RELAXED, __HIP_MEMORY_SCOPE_AGENT);
        }

        // ---- wave 0 polls spread counters with RELAXED loads ----
        if (tid < 64) {
            const unsigned int* sc =
                sub + ((size_t)b * NSUB + (tid & (NSUB - 1))) * SUBSTRIDE;
            while (true) {
                unsigned int tot = __hip_atomic_load(
                    sc, __ATOMIC_RELAXED, __HIP_MEMORY_SCOPE_AGENT);
#pragma unroll
                for (int m = 8; m > 0; m >>= 1)          // sum 16-group
                    tot += __shfl_xor(tot, m, 64);
                if (tot >= (unsigned)CC) break;
                __builtin_amdgcn_s_sleep(8);
            }
        }
        __syncthreads();
        __builtin_amdgcn_fence(__ATOMIC_ACQUIRE, "agent");       // one inv

        // ---- Phase B: gates (redundant per block, tiny) ----
        sh_s[tid]       = __hip_atomic_load(&s[b * CC + tid],
                              __ATOMIC_RELAXED, __HIP_MEMORY_SCOPE_AGENT);
        sh_s[tid + 256] = __hip_atomic_load(&s[b * CC + tid + 256],
                              __ATOMIC_RELAXED, __HIP_MEMORY_SCOPE_AGENT);
        __syncthreads();
        {
            const int j   = tid >> 3;     // 0..31
            const int seg = tid & 7;      // 0..7, 64 c's each
            const float* srow = sh_s + seg * 64;
            const float* wrow = w1 + (size_t)j * CC + seg * 64;
            float pacc = 0.0f;
#pragma unroll
            for (int c = 0; c < 64; ++c) pacc += srow[c] * wrow[c];
            part[j][seg] = pacc;
        }
        __syncthreads();
        if (tid < HH) {
            float h = b1[tid];
#pragma unroll
            for (int q = 0; q < 8; ++q) h += part[tid][q];
            sh_h[tid] = h > 0.0f ? h : 0.0f;
        }
        __syncthreads();
        if (tid == 0) {
            const int c = row & (CC - 1);
            const float* wrow = w2 + (size_t)c * HH;
            float z = b2[c];
#pragma unroll
            for (int q = 0; q < HH; ++q) z += sh_h[q] * wrow[q];
            sh_gate = 1.0f / (1.0f + expf(-z));
        }
        __syncthreads();

        // ---- Phase C: scale registers, nt-store ----
        const float gate = sh_gate;
        fv4* orr = (fv4*)(out + (size_t)row * LL);
#pragma unroll
        for (int i = 0; i < 8; ++i) {
            fv4 w = v[i] * gate;
            __builtin_nontemporal_store(w, &orr[i * NTHR + tid]);
        }
        __syncthreads();   // protect red[]/sh_* reuse next iteration
    }
}

// ---------------------------------------------------------------------------
// Fallback path (proven R3 kernels) if the cooperative launch is rejected.
// ---------------------------------------------------------------------------
__global__ __launch_bounds__(256) void k_mean(const float* __restrict__ x,
                                              float* __restrict__ s) {
    const int row = blockIdx.x;
    const int tid = threadIdx.x;
    const fv4* xr = (const fv4*)(x + (size_t)row * LL);
    float acc = 0.0f;
#pragma unroll
    for (int i = 0; i < 8; ++i) {
        fv4 v = xr[i * 256 + tid];
        acc += (v.x + v.y) + (v.z + v.w);
    }
#pragma unroll
    for (int off = 32; off > 0; off >>= 1)
        acc += __shfl_down(acc, off, 64);
    __shared__ float part[4];
    if ((tid & 63) == 0) part[tid >> 6] = acc;
    __syncthreads();
    if (tid == 0)
        s[row] = ((part[0] + part[1]) + (part[2] + part[3])) * (1.0f / (float)LL);
}

__global__ __launch_bounds__(256) void k_scale_fused(
        const float* __restrict__ x,  const float* __restrict__ s,
        const float* __restrict__ w1, const float* __restrict__ b1,
        const float* __restrict__ w2, const float* __restrict__ b2,
        float* __restrict__ out) {
    const int bid   = (int)gridDim.x - 1 - (int)blockIdx.x;
    const int b     = bid >> 7;
    const int chunk = bid & 127;
    const int tid   = threadIdx.x;
    __shared__ float partial[HH][9];
    __shared__ float h[HH];
    __shared__ float g4[4];
    {
        const int j   = tid >> 3;
        const int seg = tid & 7;
        const float* srow = s  + b * CC + seg * 64;
        const float* wrow = w1 + (size_t)j * CC + seg * 64;
        float p = 0.0f;
#pragma unroll
        for (int c = 0; c < 64; ++c) p += srow[c] * wrow[c];
        partial[j][seg] = p;
    }
    __syncthreads();
    if (tid < HH) {
        float t = b1[tid];
#pragma unroll
        for (int q = 0; q < 8; ++q) t += partial[tid][q];
        h[tid] = t > 0.0f ? t : 0.0f;
    }
    __syncthreads();
    if (tid < 4) {
        const int c = chunk * 4 + tid;
        const float* wrow = w2 + (size_t)c * HH;
        float z = b2[c];
#pragma unroll
        for (int j = 0; j < HH; ++j) z += h[j] * wrow[j];
        g4[tid] = 1.0f / (1.0f + expf(-z));
    }
    __syncthreads();
#pragma unroll
    for (int r = 0; r < 4; ++r) {
        const int c = chunk * 4 + r;
        const size_t off = ((size_t)b * CC + c) * (size_t)LL;
        const fv4* xr  = (const fv4*)(x + off);
        fv4*       orr = (fv4*)(out + off);
        const float gate = g4[r];
#pragma unroll
        for (int i = 0; i < 8; ++i) {
            fv4 v = xr[i * 256 + tid];
            v *= gate;
            __builtin_nontemporal_store(v, &orr[i * 256 + tid]);
        }
    }
}

extern "C" void kernel_launch(void* const* d_in, const int* in_sizes, int n_in,
                              void* d_out, int out_size, void* d_ws, size_t ws_size,
                              hipStream_t stream) {
    const float* x  = (const float*)d_in[0];
    const float* w1 = (const float*)d_in[1];
    const float* b1 = (const float*)d_in[2];
    const float* w2 = (const float*)d_in[3];
    const float* b2 = (const float*)d_in[4];
    float* out = (float*)d_out;

    float* s = (float*)d_ws;                       // BC floats
    unsigned int* sub = (unsigned int*)(s + BC);   // BB*NSUB*SUBSTRIDE uints

    hipMemsetAsync(sub, 0, (size_t)BB * NSUB * SUBSTRIDE * sizeof(unsigned int),
                   stream);

    void* args[] = {(void*)&x, (void*)&w1, (void*)&b1, (void*)&w2,
                    (void*)&b2, (void*)&out, (void*)&s, (void*)&sub};
    hipError_t err = hipLaunchCooperativeKernel((const void*)k_se_v3,
                                                dim3(NBLK), dim3(NTHR),
                                                args, 0, stream);
    if (err != hipSuccess) {
        k_mean       <<<BC,   256, 0, stream>>>(x, s);
        k_scale_fused<<<BC/4, 256, 0, stream>>>(x, s, w1, b1, w2, b2, out);
    }
}

// Round 11
// 139.249 us; speedup vs baseline: 7.8854x; 4.7142x over previous
//
#include <hip/hip_runtime.h>
#include <math.h>

// Problem constants
#define BB 16
#define CC 512
#define LL 8192
#define HH 32              // CC / 16
#define BC (BB * CC)
#define HALF (BC / 2)      // 4096 rows = 8 batches = 128 MiB (half of L3)

typedef float fv4 __attribute__((ext_vector_type(4)));

// ---------------------------------------------------------------------------
// Device helpers
// ---------------------------------------------------------------------------
__device__ __forceinline__ void dev_mean_row(const float* __restrict__ x,
                                             float* __restrict__ s,
                                             int row, int tid, float* red) {
    const fv4* xr = (const fv4*)(x + (size_t)row * LL);
    float acc = 0.0f;
#pragma unroll
    for (int i = 0; i < 8; ++i) {
        fv4 v = xr[i * 256 + tid];
        acc += (v.x + v.y) + (v.z + v.w);
    }
#pragma unroll
    for (int off = 32; off > 0; off >>= 1)
        acc += __shfl_down(acc, off, 64);
    if ((tid & 63) == 0) red[tid >> 6] = acc;
    __syncthreads();
    if (tid == 0)
        s[row] = ((red[0] + red[1]) + (red[2] + red[3])) * (1.0f / (float)LL);
}

// Computes gates for 4 channels (c0..c0+3) of batch b and scales those rows.
__device__ __forceinline__ void dev_scale4(
        const float* __restrict__ x,  const float* __restrict__ s,
        const float* __restrict__ w1, const float* __restrict__ b1,
        const float* __restrict__ w2, const float* __restrict__ b2,
        float* __restrict__ out, int b, int c0, int tid,
        float (*partial)[9], float* h, float* g4) {
    // h[j] = relu(b1[j] + sum_c s[b,c] * w1[j,c])
    {
        const int j   = tid >> 3;          // 0..31
        const int seg = tid & 7;           // 0..7, 64 c's each
        const float* srow = s  + b * CC + seg * 64;
        const float* wrow = w1 + (size_t)j * CC + seg * 64;
        float p = 0.0f;
#pragma unroll
        for (int c = 0; c < 64; ++c) p += srow[c] * wrow[c];
        partial[j][seg] = p;
    }
    __syncthreads();
    if (tid < HH) {
        float t = b1[tid];
#pragma unroll
        for (int q = 0; q < 8; ++q) t += partial[tid][q];
        h[tid] = t > 0.0f ? t : 0.0f;
    }
    __syncthreads();
    if (tid < 4) {
        const int c = c0 + tid;
        const float* wrow = w2 + (size_t)c * HH;
        float z = b2[c];
#pragma unroll
        for (int j = 0; j < HH; ++j) z += h[j] * wrow[j];
        g4[tid] = 1.0f / (1.0f + expf(-z));
    }
    __syncthreads();

#pragma unroll
    for (int r = 0; r < 4; ++r) {
        const int c = c0 + r;
        const size_t off = ((size_t)b * CC + c) * (size_t)LL;
        const fv4* xr  = (const fv4*)(x + off);
        fv4*       orr = (fv4*)(out + off);
        const float gate = g4[r];
#pragma unroll
        for (int i = 0; i < 8; ++i) {
            fv4 v = xr[i * 256 + tid];
            v *= gate;
            __builtin_nontemporal_store(v, &orr[i * 256 + tid]);
        }
    }
}

// ---------------------------------------------------------------------------
// D1: mean of chunk0 (rows 0..HALF-1), REVERSE order (row 0 read last ->
// newest in L3 when D2's forward scale starts).
// ---------------------------------------------------------------------------
__global__ __launch_bounds__(256) void k_mean_c0(const float* __restrict__ x,
                                                 float* __restrict__ s) {
    __shared__ float red[4];
    const int row = (int)gridDim.x - 1 - (int)blockIdx.x;   // HALF-1 .. 0
    dev_mean_row(x, s, row, threadIdx.x, red);
}

// ---------------------------------------------------------------------------
// D2: fused scale(chunk0, FORWARD) || mean(chunk1, forward).
// Scale blocks come first in the grid so they dispatch ahead of the
// eviction front created by chunk1's fill.
// ---------------------------------------------------------------------------
__global__ __launch_bounds__(256) void k_scale0_mean1(
        const float* __restrict__ x,  float* __restrict__ s,
        const float* __restrict__ w1, const float* __restrict__ b1,
        const float* __restrict__ w2, const float* __restrict__ b2,
        float* __restrict__ out) {
    __shared__ float red[4];
    __shared__ float partial[HH][9];
    __shared__ float h[HH];
    __shared__ float g4[4];
    const int tid = threadIdx.x;

    if (blockIdx.x < HALF / 4) {
        // scale chunk0: block j -> rows 4j..4j+3 (forward)
        const int j  = blockIdx.x;
        const int r0 = 4 * j;
        dev_scale4(x, s, w1, b1, w2, b2, out, r0 >> 9, r0 & (CC - 1), tid,
                   partial, h, g4);
    } else {
        // mean chunk1: rows HALF..BC-1 (forward)
        const int row = HALF + ((int)blockIdx.x - HALF / 4);
        dev_mean_row(x, s, row, tid, red);
    }
}

// ---------------------------------------------------------------------------
// D3: scale chunk1, REVERSE (row BC-1 was read most recently by D2's mean).
// ---------------------------------------------------------------------------
__global__ __launch_bounds__(256) void k_scale_c1(
        const float* __restrict__ x,  const float* __restrict__ s,
        const float* __restrict__ w1, const float* __restrict__ b1,
        const float* __restrict__ w2, const float* __restrict__ b2,
        float* __restrict__ out) {
    __shared__ float partial[HH][9];
    __shared__ float h[HH];
    __shared__ float g4[4];
    const int j  = (int)gridDim.x - 1 - (int)blockIdx.x;    // reverse
    const int r0 = HALF + 4 * j;
    dev_scale4(x, s, w1, b1, w2, b2, out, r0 >> 9, r0 & (CC - 1),
               threadIdx.x, partial, h, g4);
}

extern "C" void kernel_launch(void* const* d_in, const int* in_sizes, int n_in,
                              void* d_out, int out_size, void* d_ws, size_t ws_size,
                              hipStream_t stream) {
    const float* x  = (const float*)d_in[0];
    const float* w1 = (const float*)d_in[1];
    const float* b1 = (const float*)d_in[2];
    const float* w2 = (const float*)d_in[3];
    const float* b2 = (const float*)d_in[4];
    float* out = (float*)d_out;

    float* s = (float*)d_ws;               // BC floats

    k_mean_c0     <<<HALF,            256, 0, stream>>>(x, s);
    k_scale0_mean1<<<HALF / 4 + HALF, 256, 0, stream>>>(x, s, w1, b1, w2, b2, out);
    k_scale_c1    <<<HALF / 4,        256, 0, stream>>>(x, s, w1, b1, w2, b2, out);
}